// Round 2
// baseline (1610.092 us; speedup 1.0000x reference)
//
#include <hip/hip_runtime.h>
#include <math.h>

#define HWsz 1024
#define Nrows 16384          // B*H*W
#define NE 8192
#define Kdim 256
#define BETAF 0.25f

// ---------------- kernel 1: cc[j] = sum_k codebook[j][k]^2 ----------------
__global__ __launch_bounds__(256) void cc_kernel(const float* __restrict__ cb,
                                                 float* __restrict__ cc) {
  int wave = threadIdx.x >> 6;
  int lane = threadIdx.x & 63;
  int row = blockIdx.x * 4 + wave;
  const float4 v = *(const float4*)(cb + (size_t)row * Kdim + lane * 4);
  float s = v.x * v.x + v.y * v.y + v.z * v.z + v.w * v.w;
  for (int off = 32; off; off >>= 1) s += __shfl_down(s, off);
  if (lane == 0) cc[row] = s;
}

// ---------------- kernel 2: main VQ argmin -------------------------------
// Grid: 256 blocks x 1024 threads (16 waves). Block owns 64 rows (lane = row).
// Wave w owns codes [w*512, (w+1)*512). A (64 rows x 256 k) staged once in
// 64 KB LDS as Az[k][row] (stride-1 b32 reads, conflict-free). B (codebook)
// addresses are wave-uniform -> s_load into SGPRs; FMA uses SGPR B operand.
// Per k-step per lane: 1 ds_read_b32 feeds 16 FMAs -> VALU-bound, not LDS.
__global__ __launch_bounds__(1024) void vq_main(
    const float* __restrict__ z, const float* __restrict__ cb,
    const float* __restrict__ cc, int* __restrict__ idx_int,
    float* __restrict__ out_idxf, int* __restrict__ counts) {
  __shared__ float smem[16384];                  // 64 KB, unioned usage
  float (*Az)[64] = (float(*)[64])smem;          // [256][64] during compute
  float* redd = smem;                            // [16][64] after compute
  int* redj = (int*)(smem + 1024);               // [16][64]

  const int t = threadIdx.x;
  const int lane = t & 63;
  const int w = __builtin_amdgcn_readfirstlane(t >> 6);  // wave id, scalar
  const int bx = blockIdx.x;
  const int b = bx >> 4;
  const int hw0 = (bx & 15) << 6;
  const float* zb = z + (size_t)b * (Kdim * HWsz) + hw0;  // zb[k*HWsz + r]

  // ---- stage A: Az[k][r] = zb[k*1024 + r], 16384 floats -------------------
  {
    const int k0 = t >> 4;          // 0..63
    const int rq = (t & 15) * 4;    // 0..60
#pragma unroll
    for (int it = 0; it < 4; ++it) {
      const int k = k0 + it * 64;
      const float4 v = *(const float4*)(zb + (size_t)k * HWsz + rq);
      *(float4*)&Az[k][rq] = v;
    }
  }
  __syncthreads();

  // ---- zz for this lane's row (ascending-k fmaf chain) --------------------
  float zz = 0.f;
  for (int k = 0; k < Kdim; ++k) {
    const float a = Az[k][lane];
    zz = fmaf(a, a, zz);
  }

  // ---- scan this wave's 512 codes in groups of 16 -------------------------
  float bd = INFINITY;
  int bj = 0;
  const int code0 = w * 512;

  for (int cg = 0; cg < 32; ++cg) {
    const int j0 = code0 + cg * 16;
    const float* cbp = cb + (size_t)j0 * Kdim;   // wave-uniform base
    float acc[16];
#pragma unroll
    for (int c = 0; c < 16; ++c) acc[c] = 0.f;

    for (int kc = 0; kc < 64; ++kc) {            // chunks of 4 k
      float4 bv[16];
#pragma unroll
      for (int c = 0; c < 16; ++c)
        bv[c] = *(const float4*)(cbp + c * Kdim + kc * 4);  // uniform -> s_load
#pragma unroll
      for (int q = 0; q < 4; ++q) {
        const float a = Az[kc * 4 + q][lane];
        const float* bq0 = (const float*)&bv[0];
#pragma unroll
        for (int c = 0; c < 16; ++c)
          acc[c] = fmaf(a, ((const float*)&bv[c])[q], acc[c]);
        (void)bq0;
      }
    }
    // epilogue: d = (zz + cc_j) - 2*acc, ascending j, strict < keeps lowest
#pragma unroll
    for (int c = 0; c < 16; ++c) {
      const int j = j0 + c;
      const float d = (zz + cc[j]) - 2.0f * acc[c];
      if (d < bd) { bd = d; bj = j; }
    }
  }

  // ---- combine the 16 waves' candidates per row (reuse LDS) ---------------
  __syncthreads();                                // all Az reads done
  redd[w * 64 + lane] = bd;
  redj[w * 64 + lane] = bj;
  __syncthreads();
  if (t < 64) {
    float d0 = redd[t];
    int j0b = redj[t];
    for (int x = 1; x < 16; ++x) {
      const float d = redd[x * 64 + t];
      const int j = redj[x * 64 + t];
      if (d < d0 || (d == d0 && j < j0b)) { d0 = d; j0b = j; }
    }
    const int n = bx * 64 + t;
    idx_int[n] = j0b;
    out_idxf[n] = (float)j0b;
    atomicAdd(&counts[j0b], 1);
  }
}

// ---------------- kernel 3: gather zq (BCHW) + loss sum --------------------
__global__ __launch_bounds__(256) void vq_gather_loss(
    const float* __restrict__ z, const float* __restrict__ cb,
    const int* __restrict__ idx_int, float* __restrict__ outz,
    float* __restrict__ loss_sum) {
  const int g = blockIdx.x * 256 + threadIdx.x;  // one float4 group (b,c,hw4)
  const int hw4 = g & 255;
  const int c = (g >> 8) & 255;
  const int b = g >> 16;
  const int n = b * HWsz + hw4 * 4;
  const float4 zv = *(const float4*)(z + (size_t)g * 4);
  const int4 j4 = *(const int4*)(idx_int + n);
  float4 q;
  q.x = cb[(size_t)j4.x * Kdim + c];
  q.y = cb[(size_t)j4.y * Kdim + c];
  q.z = cb[(size_t)j4.z * Kdim + c];
  q.w = cb[(size_t)j4.w * Kdim + c];
  *(float4*)(outz + (size_t)g * 4) = q;
  float dx = q.x - zv.x, dy = q.y - zv.y, dz = q.z - zv.z, dw = q.w - zv.w;
  float s = dx * dx + dy * dy + dz * dz + dw * dw;
  for (int off = 32; off; off >>= 1) s += __shfl_down(s, off);
  __shared__ float ws4[4];
  if ((threadIdx.x & 63) == 0) ws4[threadIdx.x >> 6] = s;
  __syncthreads();
  if (threadIdx.x == 0) atomicAdd(loss_sum, (ws4[0] + ws4[1]) + (ws4[2] + ws4[3]));
}

// ---------------- kernel 4: scalars (loss, perplexity) ---------------------
__global__ __launch_bounds__(256) void vq_final(const int* __restrict__ counts,
                                                const float* __restrict__ loss_sum,
                                                float* __restrict__ out_sc) {
  float h = 0.f;
  for (int i = threadIdx.x; i < NE; i += 256) {
    float p = (float)counts[i] * (1.0f / 16384.0f);
    h += p * logf(p + 1e-10f);
  }
  for (int off = 32; off; off >>= 1) h += __shfl_down(h, off);
  __shared__ float hs[4];
  if ((threadIdx.x & 63) == 0) hs[threadIdx.x >> 6] = h;
  __syncthreads();
  if (threadIdx.x == 0) {
    float H = (hs[0] + hs[1]) + (hs[2] + hs[3]);
    float m = loss_sum[0] * (1.0f / 4194304.0f);
    out_sc[0] = m + BETAF * m;   // embedding_loss + BETA*commitment_loss (equal fwd)
    out_sc[1] = expf(-H);
  }
}

extern "C" void kernel_launch(void* const* d_in, const int* in_sizes, int n_in,
                              void* d_out, int out_size, void* d_ws, size_t ws_size,
                              hipStream_t stream) {
  const float* z = (const float*)d_in[0];
  const float* cb = (const float*)d_in[1];
  float* out = (float*)d_out;
  float* out_zq = out;                     // 4194304
  float* out_sc = out + 4194304;           // loss, perplexity
  float* out_idx = out + 4194306;          // 16384 (idx as float)

  char* w = (char*)d_ws;
  float* cc = (float*)w;        w += (size_t)NE * 4;
  int* idx_int = (int*)w;       w += (size_t)Nrows * 4;
  int* counts = (int*)w;        w += (size_t)NE * 4;
  float* loss_sum = (float*)w;  w += 4;

  hipMemsetAsync(counts, 0, (size_t)NE * 4, stream);
  hipMemsetAsync(loss_sum, 0, 4, stream);

  cc_kernel<<<NE / 4, 256, 0, stream>>>(cb, cc);
  vq_main<<<256, 1024, 0, stream>>>(z, cb, cc, idx_int, out_idx, counts);
  vq_gather_loss<<<4096, 256, 0, stream>>>(z, cb, idx_int, out_zq, loss_sum);
  vq_final<<<1, 256, 0, stream>>>(counts, loss_sum, out_sc);
}

// Round 3
// 680.323 us; speedup vs baseline: 2.3667x; 2.3667x over previous
//
#include <hip/hip_runtime.h>
#include <math.h>

#define HWsz 1024
#define Nrows 16384          // B*H*W
#define NE 8192
#define Kdim 256
#define BETAF 0.25f

typedef __attribute__((ext_vector_type(8))) short bf16x8;
typedef __attribute__((ext_vector_type(16))) float f32x16;

__device__ inline unsigned short bf16_rne(float x) {
  unsigned int u = __float_as_uint(x);
  return (unsigned short)((u + 0x7FFFu + ((u >> 16) & 1u)) >> 16);
}
__device__ inline float bf16_tof(unsigned short h) {
  return __uint_as_float(((unsigned int)h) << 16);
}
__device__ inline void gll16(const void* g, void* l) {
  __builtin_amdgcn_global_load_lds(
      (const __attribute__((address_space(1))) unsigned int*)g,
      (__attribute__((address_space(3))) unsigned int*)l, 16, 0, 0);
}

// ---- kernel P: codebook -> bf16 splits C0/C1/C2 + cc (cc identical to r1) --
__global__ __launch_bounds__(256) void conv_cb(
    const float* __restrict__ cb, unsigned short* __restrict__ C0,
    unsigned short* __restrict__ C1, unsigned short* __restrict__ C2,
    float* __restrict__ cc) {
  const int wave = threadIdx.x >> 6, lane = threadIdx.x & 63;
  const int j = blockIdx.x * 4 + wave;
  const size_t base = (size_t)j * Kdim + lane * 4;
  const float4 v = *(const float4*)(cb + base);
  float s = v.x * v.x + v.y * v.y + v.z * v.z + v.w * v.w;
  for (int off = 32; off; off >>= 1) s += __shfl_down(s, off);
  if (lane == 0) cc[j] = s;
  const float vv[4] = {v.x, v.y, v.z, v.w};
  unsigned short a0[4], a1[4], a2[4];
#pragma unroll
  for (int i = 0; i < 4; ++i) {
    const float f = vv[i];
    const unsigned short q0 = bf16_rne(f);
    const float r1 = f - bf16_tof(q0);
    const unsigned short q1 = bf16_rne(r1);
    const float r2 = r1 - bf16_tof(q1);
    a0[i] = q0; a1[i] = q1; a2[i] = bf16_rne(r2);
  }
  *(ushort4*)(C0 + base) = *(ushort4*)a0;
  *(ushort4*)(C1 + base) = *(ushort4*)a1;
  *(ushort4*)(C2 + base) = *(ushort4*)a2;
}

// ---- kernel T: z (B,C,H,W) -> transposed bf16 splits Z0/Z1/Z2 [n][k] + zz --
// zz uses the identical ascending-k fmaf chain that passed in rounds 1-2.
__global__ __launch_bounds__(256) void conv_z(
    const float* __restrict__ z, unsigned short* __restrict__ Z0,
    unsigned short* __restrict__ Z1, unsigned short* __restrict__ Z2,
    float* __restrict__ zz) {
  __shared__ float tile[64][68];   // 64 k x 64 rows, padded
  const int t = threadIdx.x;
  const int bid = blockIdx.x;
  const int n0 = bid * 64;
  const int b = bid >> 4;
  const int hw0 = (bid & 15) << 6;
  const float* zb = z + (size_t)b * (Kdim * HWsz) + hw0;
  float zzacc = 0.f;
  const int rr = t >> 2, kq = (t & 3) * 16;
  for (int kc = 0; kc < 4; ++kc) {
#pragma unroll
    for (int i = 0; i < 16; ++i) {
      const int idx = i * 256 + t;
      const int k = idx >> 6, r = idx & 63;
      tile[r][k] = zb[(size_t)(kc * 64 + k) * HWsz + r];
    }
    __syncthreads();
    if (t < 64) {
      for (int k = 0; k < 64; ++k) {
        const float a = tile[t][k];
        zzacc = fmaf(a, a, zzacc);
      }
    }
    unsigned short h0[16], h1[16], h2[16];
#pragma unroll
    for (int i = 0; i < 16; ++i) {
      const float f = tile[rr][kq + i];
      const unsigned short q0 = bf16_rne(f);
      const float r1 = f - bf16_tof(q0);
      const unsigned short q1 = bf16_rne(r1);
      const float r2 = r1 - bf16_tof(q1);
      h0[i] = q0; h1[i] = q1; h2[i] = bf16_rne(r2);
    }
    const size_t go = (size_t)(n0 + rr) * Kdim + kc * 64 + kq;
#pragma unroll
    for (int i4 = 0; i4 < 4; ++i4) {
      *(ushort4*)(Z0 + go + i4 * 4) = *(ushort4*)&h0[i4 * 4];
      *(ushort4*)(Z1 + go + i4 * 4) = *(ushort4*)&h1[i4 * 4];
      *(ushort4*)(Z2 + go + i4 * 4) = *(ushort4*)&h2[i4 * 4];
    }
    __syncthreads();
  }
  if (t < 64) zz[n0 + t] = zzacc;
}

// ---- kernel G: bf16x3-split MFMA GEMM + fused argmin ----------------------
// grid 1024 = 128 row-tiles x 8 code-groups (ctg = bid&7 -> XCD-resident
// codebook slice). Block: 256 thr / 4 waves (2x2 over 128x128 tile).
// MFMA 32x32x16_bf16; A = codes, B = z-rows; 6 products emulate fp32.
__global__ __launch_bounds__(256, 1) void vq_gemm(
    const unsigned short* __restrict__ C0, const unsigned short* __restrict__ C1,
    const unsigned short* __restrict__ C2, const unsigned short* __restrict__ Z0,
    const unsigned short* __restrict__ Z1, const unsigned short* __restrict__ Z2,
    const float* __restrict__ cc, const float* __restrict__ zz,
    float* __restrict__ pd, int* __restrict__ pj) {
  __shared__ unsigned short Alds[12288];  // [arr][kk][rg][lane][8] 24KB
  __shared__ unsigned short Blds[12288];
  __shared__ float ccs[128];
  __shared__ float redD[2][128];
  __shared__ int redJ[2][128];

  const int t = threadIdx.x;
  const int lane = t & 63;
  const int w = __builtin_amdgcn_readfirstlane(t >> 6);
  const int wc = w & 1, wr = w >> 1;
  const int bid = blockIdx.x;
  const int ctg = bid & 7;
  const int rt = bid >> 3;

  const int laneA = (lane & 31) * Kdim + (lane >> 5) * 8;  // ushort offset

  const unsigned short* const Cab[3] = {C0, C1, C2};
  const unsigned short* const Zab[3] = {Z0, Z1, Z2};

  float zzv[2];
#pragma unroll
  for (int ri = 0; ri < 2; ++ri)
    zzv[ri] = zz[rt * 128 + wr * 64 + ri * 32 + (lane & 31)];

  float bd[2] = {INFINITY, INFINITY};
  int bj[2] = {0, 0};
  const f32x16 zero16 = {0,0,0,0,0,0,0,0,0,0,0,0,0,0,0,0};

  for (int ct8 = 0; ct8 < 8; ++ct8) {
    const int ct = ctg * 8 + ct8;
    if (t < 128) ccs[t] = cc[ct * 128 + t];

    f32x16 acc[2][2];
    acc[0][0] = zero16; acc[0][1] = zero16; acc[1][0] = zero16; acc[1][1] = zero16;

    for (int ch = 0; ch < 8; ++ch) {
      // stage: 48 frag-groups (24 A + 24 B), 12 per wave, via global_load_lds
      const int s0 = w * 12;
#pragma unroll
      for (int i = 0; i < 12; ++i) {
        const int s = s0 + i;
        const int isB = (s >= 24) ? 1 : 0;
        const int idx = isB ? (s - 24) : s;
        const int arr = idx >> 3, kk = (idx >> 2) & 1, rg = idx & 3;
        const int grp = (arr * 2 + kk) * 4 + rg;
        if (!isB) {
          const int go = (ct * 128 + rg * 32) * Kdim + ch * 32 + kk * 16;
          gll16(Cab[arr] + go + laneA, &Alds[grp * 512]);
        } else {
          const int go = (rt * 128 + rg * 32) * Kdim + ch * 32 + kk * 16;
          gll16(Zab[arr] + go + laneA, &Blds[grp * 512]);
        }
      }
      __syncthreads();   // compiler drains vmcnt before barrier

#pragma unroll
      for (int kk = 0; kk < 2; ++kk) {
        bf16x8 af[3][2], bfr[3][2];
#pragma unroll
        for (int arr = 0; arr < 3; ++arr) {
#pragma unroll
          for (int h = 0; h < 2; ++h) {
            af[arr][h] = *(const bf16x8*)&Alds[((arr * 2 + kk) * 4 + wc * 2 + h) * 512 + lane * 8];
            bfr[arr][h] = *(const bf16x8*)&Blds[((arr * 2 + kk) * 4 + wr * 2 + h) * 512 + lane * 8];
          }
        }
#define PROD(pa, pb) \
  acc[0][0] = __builtin_amdgcn_mfma_f32_32x32x16_bf16(af[pa][0], bfr[pb][0], acc[0][0], 0, 0, 0); \
  acc[0][1] = __builtin_amdgcn_mfma_f32_32x32x16_bf16(af[pa][0], bfr[pb][1], acc[0][1], 0, 0, 0); \
  acc[1][0] = __builtin_amdgcn_mfma_f32_32x32x16_bf16(af[pa][1], bfr[pb][0], acc[1][0], 0, 0, 0); \
  acc[1][1] = __builtin_amdgcn_mfma_f32_32x32x16_bf16(af[pa][1], bfr[pb][1], acc[1][1], 0, 0, 0);
        PROD(0, 0) PROD(0, 1) PROD(1, 0) PROD(1, 1) PROD(0, 2) PROD(2, 0)
#undef PROD
      }
      __syncthreads();
    }

    // epilogue: d = (zz + cc) - 2*acc (same expression shape as r1/r2)
#pragma unroll
    for (int ri = 0; ri < 2; ++ri) {
#pragma unroll
      for (int ci = 0; ci < 2; ++ci) {
#pragma unroll
        for (int reg = 0; reg < 16; ++reg) {
          const int cl = wc * 64 + ci * 32 + (reg & 3) + ((reg >> 2) * 8) + ((lane >> 5) * 4);
          const float ccv = ccs[cl];
          const float av = acc[ci][ri][reg];
          const float tzc = zzv[ri] + ccv;
          const float d = tzc - 2.0f * av;
          const int j = ct * 128 + cl;
          if (d < bd[ri]) { bd[ri] = d; bj[ri] = j; }   // ascending-j scan
        }
      }
    }
    __syncthreads();   // ccs reads done before next ct8 overwrites
  }

  // combine lane-halves (same z-row, complementary code sets mod 8)
#pragma unroll
  for (int ri = 0; ri < 2; ++ri) {
    const float od = __shfl_xor(bd[ri], 32);
    const int oj = __shfl_xor(bj[ri], 32);
    if (od < bd[ri] || (od == bd[ri] && oj < bj[ri])) { bd[ri] = od; bj[ri] = oj; }
    if (lane < 32) {
      redD[wc][wr * 64 + ri * 32 + lane] = bd[ri];
      redJ[wc][wr * 64 + ri * 32 + lane] = bj[ri];
    }
  }
  __syncthreads();
  if (t < 128) {
    float d0 = redD[0][t];
    int j0 = redJ[0][t];
    const float d1 = redD[1][t];
    const int j1 = redJ[1][t];
    if (d1 < d0 || (d1 == d0 && j1 < j0)) { d0 = d1; j0 = j1; }
    const int n = rt * 128 + t;
    pd[ctg * Nrows + n] = d0;
    pj[ctg * Nrows + n] = j0;
  }
}

// ---- combine 8 code-group partials -> idx, counts -------------------------
__global__ __launch_bounds__(256) void vq_combine(const float* __restrict__ pd,
                                                  const int* __restrict__ pj,
                                                  int* __restrict__ idx_int,
                                                  float* __restrict__ out_idxf,
                                                  int* __restrict__ counts) {
  const int n = blockIdx.x * 256 + threadIdx.x;
  float d0 = pd[n];
  int j0 = pj[n];
  for (int s = 1; s < 8; ++s) {
    const float d = pd[(size_t)s * Nrows + n];
    const int j = pj[(size_t)s * Nrows + n];
    if (d < d0 || (d == d0 && j < j0)) { d0 = d; j0 = j; }
  }
  idx_int[n] = j0;
  out_idxf[n] = (float)j0;
  atomicAdd(&counts[j0], 1);
}

// ---- gather zq (BCHW) + loss sum (unchanged, passed r1/r2) ----------------
__global__ __launch_bounds__(256) void vq_gather_loss(
    const float* __restrict__ z, const float* __restrict__ cb,
    const int* __restrict__ idx_int, float* __restrict__ outz,
    float* __restrict__ loss_sum) {
  const int g = blockIdx.x * 256 + threadIdx.x;
  const int hw4 = g & 255;
  const int c = (g >> 8) & 255;
  const int b = g >> 16;
  const int n = b * HWsz + hw4 * 4;
  const float4 zv = *(const float4*)(z + (size_t)g * 4);
  const int4 j4 = *(const int4*)(idx_int + n);
  float4 q;
  q.x = cb[(size_t)j4.x * Kdim + c];
  q.y = cb[(size_t)j4.y * Kdim + c];
  q.z = cb[(size_t)j4.z * Kdim + c];
  q.w = cb[(size_t)j4.w * Kdim + c];
  *(float4*)(outz + (size_t)g * 4) = q;
  float dx = q.x - zv.x, dy = q.y - zv.y, dz = q.z - zv.z, dw = q.w - zv.w;
  float s = dx * dx + dy * dy + dz * dz + dw * dw;
  for (int off = 32; off; off >>= 1) s += __shfl_down(s, off);
  __shared__ float ws4[4];
  if ((threadIdx.x & 63) == 0) ws4[threadIdx.x >> 6] = s;
  __syncthreads();
  if (threadIdx.x == 0) atomicAdd(loss_sum, (ws4[0] + ws4[1]) + (ws4[2] + ws4[3]));
}

// ---- scalars (unchanged) --------------------------------------------------
__global__ __launch_bounds__(256) void vq_final(const int* __restrict__ counts,
                                                const float* __restrict__ loss_sum,
                                                float* __restrict__ out_sc) {
  float h = 0.f;
  for (int i = threadIdx.x; i < NE; i += 256) {
    float p = (float)counts[i] * (1.0f / 16384.0f);
    h += p * logf(p + 1e-10f);
  }
  for (int off = 32; off; off >>= 1) h += __shfl_down(h, off);
  __shared__ float hs[4];
  if ((threadIdx.x & 63) == 0) hs[threadIdx.x >> 6] = h;
  __syncthreads();
  if (threadIdx.x == 0) {
    float H = (hs[0] + hs[1]) + (hs[2] + hs[3]);
    float m = loss_sum[0] * (1.0f / 4194304.0f);
    out_sc[0] = m + BETAF * m;
    out_sc[1] = expf(-H);
  }
}

extern "C" void kernel_launch(void* const* d_in, const int* in_sizes, int n_in,
                              void* d_out, int out_size, void* d_ws, size_t ws_size,
                              hipStream_t stream) {
  const float* z = (const float*)d_in[0];
  const float* cb = (const float*)d_in[1];
  float* out = (float*)d_out;
  float* out_zq = out;                     // 4194304
  float* out_sc = out + 4194304;           // loss, perplexity
  float* out_idx = out + 4194306;          // 16384 idx as float

  char* wp = (char*)d_ws;
  unsigned short* C0 = (unsigned short*)wp; wp += (size_t)NE * Kdim * 2;
  unsigned short* C1 = (unsigned short*)wp; wp += (size_t)NE * Kdim * 2;
  unsigned short* C2 = (unsigned short*)wp; wp += (size_t)NE * Kdim * 2;
  unsigned short* Z0 = (unsigned short*)wp; wp += (size_t)Nrows * Kdim * 2;
  unsigned short* Z1 = (unsigned short*)wp; wp += (size_t)Nrows * Kdim * 2;
  unsigned short* Z2 = (unsigned short*)wp; wp += (size_t)Nrows * Kdim * 2;
  float* cc = (float*)wp;       wp += (size_t)NE * 4;
  float* zz = (float*)wp;       wp += (size_t)Nrows * 4;
  float* pd = (float*)wp;       wp += (size_t)8 * Nrows * 4;
  int* pj = (int*)wp;           wp += (size_t)8 * Nrows * 4;
  int* idx_int = (int*)wp;      wp += (size_t)Nrows * 4;
  int* counts = (int*)wp;       wp += (size_t)NE * 4;
  float* loss_sum = (float*)wp; wp += 64;

  hipMemsetAsync(counts, 0, (size_t)NE * 4, stream);
  hipMemsetAsync(loss_sum, 0, 4, stream);

  conv_cb<<<NE / 4, 256, 0, stream>>>(cb, C0, C1, C2, cc);
  conv_z<<<Nrows / 64, 256, 0, stream>>>(z, Z0, Z1, Z2, zz);
  vq_gemm<<<1024, 256, 0, stream>>>(C0, C1, C2, Z0, Z1, Z2, cc, zz, pd, pj);
  vq_combine<<<Nrows / 256, 256, 0, stream>>>(pd, pj, idx_int, out_idx, counts);
  vq_gather_loss<<<4096, 256, 0, stream>>>(z, cb, idx_int, out_zq, loss_sum);
  vq_final<<<1, 256, 0, stream>>>(counts, loss_sum, out_sc);
}